// Round 2
// baseline (332.796 us; speedup 1.0000x reference)
//
#include <hip/hip_runtime.h>
#include <hip/hip_bf16.h>
#include <stddef.h>

// ---------------- problem constants ----------------
#define NTOK   16384          // b*n = 4*4096
#define SEQN   4096
#define DIM    1024
#define K3     3072           // 3*DIM
#define HEADS  16
#define HD     64             // head dim

typedef __attribute__((ext_vector_type(8)))  short  short8;
typedef __attribute__((ext_vector_type(4)))  float  float4v;

static __device__ __forceinline__ unsigned short f32_to_bf16_bits(float f) {
    unsigned u = __float_as_uint(f);
    unsigned r = u + 0x7fffu + ((u >> 16) & 1u);   // RNE
    return (unsigned short)(r >> 16);
}
static __device__ __forceinline__ unsigned pack_bf16x2(float lo, float hi) {
    return (unsigned)f32_to_bf16_bits(lo) | ((unsigned)f32_to_bf16_bits(hi) << 16);
}
static __device__ __forceinline__ void unpack_bf16x8(uint4 u, float* f) {
    f[0] = __uint_as_float(u.x << 16); f[1] = __uint_as_float(u.x & 0xffff0000u);
    f[2] = __uint_as_float(u.y << 16); f[3] = __uint_as_float(u.y & 0xffff0000u);
    f[4] = __uint_as_float(u.z << 16); f[5] = __uint_as_float(u.z & 0xffff0000u);
    f[6] = __uint_as_float(u.w << 16); f[7] = __uint_as_float(u.w & 0xffff0000u);
}

// async global->LDS DMA, 16B per lane, LDS dst = uniform base + lane*16
typedef const void __attribute__((address_space(1)))* gas_ptr;
typedef void __attribute__((address_space(3)))* las_ptr;
static __device__ __forceinline__ void gload_lds16(const unsigned short* g,
                                                   unsigned short* l) {
    __builtin_amdgcn_global_load_lds((gas_ptr)g, (las_ptr)l, 16, 0, 0);
}

// ---------------- prep: fp32 -> bf16 cast (vectorized) ----------------
__global__ void cvt_f32_bf16(const float4* __restrict__ in,
                             ushort4* __restrict__ out, int n4) {
    int i = blockIdx.x * blockDim.x + threadIdx.x;
    if (i < n4) {
        float4 v = in[i];
        ushort4 o;
        o.x = f32_to_bf16_bits(v.x);
        o.y = f32_to_bf16_bits(v.y);
        o.z = f32_to_bf16_bits(v.z);
        o.w = f32_to_bf16_bits(v.w);
        out[i] = o;
    }
}

// ---------------- prep: transpose K x N fp32 -> N x K bf16 ----------------
__global__ void transpose_cvt(const float* __restrict__ in,
                              unsigned short* __restrict__ out,
                              int K, int N) {
    __shared__ float t[32][33];
    int n0 = blockIdx.x * 32, k0 = blockIdx.y * 32;
    int tx = threadIdx.x, ty = threadIdx.y;     // block (32,8)
    #pragma unroll
    for (int r = ty; r < 32; r += 8)
        t[r][tx] = in[(size_t)(k0 + r) * N + n0 + tx];
    __syncthreads();
    #pragma unroll
    for (int r = ty; r < 32; r += 8)
        out[(size_t)(n0 + r) * K + k0 + tx] = f32_to_bf16_bits(t[tx][r]);
}

// ============ 256x256 8-phase bf16 GEMM (m201 template, K=1024) ============
// C[M,N] = A[M,K] * Bt[N,K]^T.  512 thr = 8 waves (2M x 4N), each wave a
// 128x64 output strip of 8x4 16x16 fragments.  BK=64, double-buffered
// 128 KiB LDS.  Per K-tile: 4 phases (quadrants (0,0)->(0,1)->(1,1)->(1,0),
// B0 frags held in regs so q3 does 0 ds_reads).  Staging runs 3-4 stage
// units ahead via global_load_lds with counted vmcnt(6) ONLY at phases 4/8
// (T4).  Stage units are the row sets retired by phase parity so every unit
// is staged >=1 barrier-separated phase after its last read.
// XOR swizzle chunk^=(row&7) applied on the GLOBAL side of the DMA (LDS dst
// linear, m104/m108) and mirrored in fragment reads; 16x16x32 frag reads
// span 16 rows -> 2-way bank alias = free (m136; R1 counter: 0 conflicts).
// R2 change: NO sched_barrier(0), NO explicit lgkmcnt(0) — all ds_reads are
// C++ loads so the compiler emits its own fine-grained lgkmcnt interleave
// (m97/m141 lesson; m201 template has no sched walls either).
template<int WITH_BIAS>
__global__ __launch_bounds__(512, 2) void gemm_bf16_256(
    const unsigned short* __restrict__ A,
    const unsigned short* __restrict__ Bt,
    void* __restrict__ Cout,
    const float* __restrict__ bias,
    int M, int N)
{
    constexpr int K = 1024;            // both GEMMs have K=1024
    __shared__ unsigned short As[2][256][64];   // 64 KiB
    __shared__ unsigned short Bs[2][256][64];   // 64 KiB

    const int tid  = threadIdx.x;
    const int wave = tid >> 6;
    const int lane = tid & 63;
    const int wm   = wave >> 2;        // 0..1
    const int wn   = wave & 3;         // 0..3
    const int l15  = lane & 15;
    const int l4   = lane >> 4;        // 0..3
    const int l7   = lane & 7;

    // T1: bijective XCD swizzle (grid % 8 == 0 at both call sites)
    const int nwg = (int)gridDim.x;
    const int bid = (int)blockIdx.x;
    const int swz = (bid & 7) * (nwg >> 3) + (bid >> 3);
    const int ntn = N >> 8;
    const int rowBase = (swz / ntn) << 8;
    const int colBase = (swz % ntn) << 8;
    (void)M;

    // staging lane geometry: 1 issue = 8 rows x 128 B
    const int drow = lane >> 3;        // 0..7
    const int lc   = l7 ^ drow;        // logical chunk fetched (pre-swizzle)
    const unsigned short* gA = A  + (size_t)(rowBase + drow) * K + lc * 8;
    const unsigned short* gB = Bt + (size_t)(colBase + drow) * K + lc * 8;

    float4v acc[8][4];
    #pragma unroll
    for (int m = 0; m < 8; m++)
        #pragma unroll
        for (int n = 0; n < 4; n++) acc[m][n] = (float4v)0.0f;

    short8 aF[4][2], b0F[2][2], b1F[2][2];

// ---- stage macros: one unit = 128 rows = 2 issues/wave (16 rows) ----
#define STG_A(f, oddH, T) do {                                               \
    const int ra_ = ((wave >> 2) * 128) + (oddH) * 64 + (wave & 3) * 16;     \
    gload_lds16(gA + (size_t)(ra_    ) * K + (size_t)(T) * 64, &As[f][ra_    ][0]); \
    gload_lds16(gA + (size_t)(ra_ + 8) * K + (size_t)(T) * 64, &As[f][ra_ + 8][0]); \
  } while (0)
#define STG_B(f, oddH, T) do {                                               \
    const int rb_ = ((wave >> 1) * 64) + (oddH) * 32 + (wave & 1) * 16;      \
    gload_lds16(gB + (size_t)(rb_    ) * K + (size_t)(T) * 64, &Bs[f][rb_    ][0]); \
    gload_lds16(gB + (size_t)(rb_ + 8) * K + (size_t)(T) * 64, &Bs[f][rb_ + 8][0]); \
  } while (0)

// ---- fragment reads (ds_read_b128, swizzled): chunk = kc*4+l4 ^ (row&7) ----
#define RD_A(f, a) do {                                                      \
    _Pragma("unroll")                                                        \
    for (int ra = 0; ra < 4; ra++) {                                         \
      const unsigned short* r_ = &As[f][wm * 128 + (a) * 64 + ra * 16 + l15][0]; \
      aF[ra][0] = *(const short8*)(r_ + (((    l4) ^ l7) * 8));              \
      aF[ra][1] = *(const short8*)(r_ + (((4 + l4) ^ l7) * 8));              \
    } } while (0)
#define RD_B(f, b, dst) do {                                                 \
    _Pragma("unroll")                                                        \
    for (int cb = 0; cb < 2; cb++) {                                         \
      const unsigned short* r_ = &Bs[f][wn * 64 + (b) * 32 + cb * 16 + l15][0]; \
      dst[cb][0] = *(const short8*)(r_ + (((    l4) ^ l7) * 8));             \
      dst[cb][1] = *(const short8*)(r_ + (((4 + l4) ^ l7) * 8));             \
    } } while (0)

// ---- one quadrant = 16 MFMA ----
#define MM(a, b, bF) do {                                                    \
    _Pragma("unroll")                                                        \
    for (int ra = 0; ra < 4; ra++)                                           \
      _Pragma("unroll")                                                      \
      for (int cb = 0; cb < 2; cb++) {                                       \
        acc[(a)*4+ra][(b)*2+cb] = __builtin_amdgcn_mfma_f32_16x16x32_bf16(   \
            aF[ra][0], bF[cb][0], acc[(a)*4+ra][(b)*2+cb], 0, 0, 0);         \
        acc[(a)*4+ra][(b)*2+cb] = __builtin_amdgcn_mfma_f32_16x16x32_bf16(   \
            aF[ra][1], bF[cb][1], acc[(a)*4+ra][(b)*2+cb], 0, 0, 0);         \
      } } while (0)

#define BAR()   __builtin_amdgcn_s_barrier()
#define VM(n)   asm volatile("s_waitcnt vmcnt(" #n ")" ::: "memory")
#define P1()    __builtin_amdgcn_s_setprio(1)
#define P0()    __builtin_amdgcn_s_setprio(0)

    // ---- prologue: tile0 fully; tile1 A-even,B-even,B-odd ----
    STG_A(0,0,0); STG_B(0,0,0); STG_B(0,1,0); STG_A(0,1,0);
    STG_A(1,0,1); STG_B(1,0,1); STG_B(1,1,1);
    VM(6);                       // tile0 (oldest 8) landed; 3 units in flight
    BAR();

    // ---- main loop: 7 iterations x 2 K-tiles (tiles 0..13) ----
    #pragma unroll 1
    for (int i = 0; i < 7; i++) {
        const int t1 = 2 * i + 1;
        // ---------- K-tile 2i (buf0), quadrants (0,0)(0,1)(1,1)(1,0) -------
        RD_A(0,0); RD_B(0,0,b0F); STG_A(1,1,t1);
        BAR(); P1(); MM(0,0,b0F); P0(); BAR();
        RD_B(0,1,b1F);            STG_A(0,0,t1+1);
        BAR(); P1(); MM(0,1,b1F); P0(); BAR();
        RD_A(0,1);                STG_B(0,0,t1+1);
        BAR(); P1(); MM(1,1,b1F); P0(); BAR();
                                  STG_B(0,1,t1+1); VM(6);
        BAR(); P1(); MM(1,0,b0F); P0(); BAR();
        // ---------- K-tile 2i+1 (buf1) ------------------------------------
        RD_A(1,0); RD_B(1,0,b0F); STG_A(0,1,t1+1);
        BAR(); P1(); MM(0,0,b0F); P0(); BAR();
        RD_B(1,1,b1F);            STG_A(1,0,t1+2);
        BAR(); P1(); MM(0,1,b1F); P0(); BAR();
        RD_A(1,1);                STG_B(1,0,t1+2);
        BAR(); P1(); MM(1,1,b1F); P0(); BAR();
                                  STG_B(1,1,t1+2); VM(6);
        BAR(); P1(); MM(1,0,b0F); P0(); BAR();
    }

    // ---- tail: tiles 14,15 — only p0 stages (A-odd of 15); vmcnt(0) @ p3 --
    {
        RD_A(0,0); RD_B(0,0,b0F); STG_A(1,1,15);
        BAR(); P1(); MM(0,0,b0F); P0(); BAR();
        RD_B(0,1,b1F);
        BAR(); P1(); MM(0,1,b1F); P0(); BAR();
        RD_A(0,1);
        BAR(); P1(); MM(1,1,b1F); P0(); BAR();
        VM(0);                    // all of tile 15 landed
        BAR(); P1(); MM(1,0,b0F); P0(); BAR();
        // tile 15: no LDS writes remain -> no barriers needed
        RD_A(1,0); RD_B(1,0,b0F); P1(); MM(0,0,b0F); P0();
        RD_B(1,1,b1F);            P1(); MM(0,1,b1F); P0();
        RD_A(1,1);                P1(); MM(1,1,b1F); P0();
                                  P1(); MM(1,0,b0F); P0();
    }

    // ---- epilogue: D col = lane&15, row = (lane>>4)*4 + reg ----
    #pragma unroll
    for (int m = 0; m < 8; m++) {
        const int row = rowBase + wm * 128 + m * 16 + l4 * 4;
        #pragma unroll
        for (int n = 0; n < 4; n++) {
            const int col = colBase + wn * 64 + n * 16 + l15;
            if (WITH_BIAS) {
                const float bv = bias[col];
                #pragma unroll
                for (int r = 0; r < 4; r++)
                    ((float*)Cout)[(size_t)(row + r) * N + col] = acc[m][n][r] + bv;
            } else {
                #pragma unroll
                for (int r = 0; r < 4; r++)
                    ((unsigned short*)Cout)[(size_t)(row + r) * N + col] =
                        f32_to_bf16_bits(acc[m][n][r]);
            }
        }
    }
#undef STG_A
#undef STG_B
#undef RD_A
#undef RD_B
#undef MM
#undef BAR
#undef VM
#undef P1
#undef P0
}

// ---------------- per-token attention: wave-per-token, barrier-free --------
__global__ __launch_bounds__(256) void attn_tok(
    const unsigned short* __restrict__ qkv,   // NTOK x 3072 bf16
    const float* __restrict__ fcos,           // 4096 x 32
    const float* __restrict__ fsin,
    const float* __restrict__ gq,             // 64
    const float* __restrict__ gk,
    unsigned short* __restrict__ outb)        // NTOK x 1024 bf16
{
    __shared__ float kl[4][16][68];   // [wave][g][dim] stride 68: 2-way alias
    __shared__ float vl[4][16][68];

    const int tid  = threadIdx.x;
    const int wv   = tid >> 6;
    const int lane = tid & 63;
    const int h    = lane & 15;
    const int p    = lane >> 4;
    const int tok  = blockIdx.x * 4 + wv;
    const int n    = tok & (SEQN - 1);

    const unsigned short* base = qkv + (size_t)tok * K3 + h * 64 + p * 16;
    uint4 qr0 = *(const uint4*)(base);
    uint4 qr1 = *(const uint4*)(base + 8);
    uint4 kr0 = *(const uint4*)(base + DIM);
    uint4 kr1 = *(const uint4*)(base + DIM + 8);
    uint4 vr0 = *(const uint4*)(base + 2 * DIM);
    uint4 vr1 = *(const uint4*)(base + 2 * DIM + 8);

    float q[16], k[16], v[16];
    unpack_bf16x8(qr0, q); unpack_bf16x8(qr1, q + 8);
    unpack_bf16x8(kr0, k); unpack_bf16x8(kr1, k + 8);
    unpack_bf16x8(vr0, v); unpack_bf16x8(vr1, v + 8);

    // RMSNorm over the 64-dim head (reduce across the 4 p-slices)
    float ssq = 0.f, ssk = 0.f;
    #pragma unroll
    for (int i = 0; i < 16; i++) { ssq += q[i] * q[i]; ssk += k[i] * k[i]; }
    ssq += __shfl_xor(ssq, 16); ssq += __shfl_xor(ssq, 32);
    ssk += __shfl_xor(ssk, 16); ssk += __shfl_xor(ssk, 32);
    const float sq = 1.0f / (sqrtf(ssq) * 0.125f + 1e-6f);
    const float sk = 1.0f / (sqrtf(ssk) * 0.125f + 1e-6f);

    #pragma unroll
    for (int c = 0; c < 4; c++) {
        float4 gg = *(const float4*)(gq + p * 16 + c * 4);
        float4 gh = *(const float4*)(gk + p * 16 + c * 4);
        q[c*4+0] *= sq * gg.x; q[c*4+1] *= sq * gg.y;
        q[c*4+2] *= sq * gg.z; q[c*4+3] *= sq * gg.w;
        k[c*4+0] *= sk * gh.x; k[c*4+1] *= sk * gh.y;
        k[c*4+2] *= sk * gh.z; k[c*4+3] *= sk * gh.w;
    }

    // RoPE: local pair j -> global pair index 8p+j
    {
        const float* cb = fcos + n * 32 + p * 8;
        const float* sb = fsin + n * 32 + p * 8;
        float4 c0 = *(const float4*)cb, c1 = *(const float4*)(cb + 4);
        float4 s0 = *(const float4*)sb, s1 = *(const float4*)(sb + 4);
        float cs[8] = {c0.x,c0.y,c0.z,c0.w,c1.x,c1.y,c1.z,c1.w};
        float sn[8] = {s0.x,s0.y,s0.z,s0.w,s1.x,s1.y,s1.z,s1.w};
        #pragma unroll
        for (int j = 0; j < 8; j++) {
            float re = q[2*j], im = q[2*j+1];
            q[2*j]   = re * cs[j] - im * sn[j];
            q[2*j+1] = re * sn[j] + im * cs[j];
            re = k[2*j]; im = k[2*j+1];
            k[2*j]   = re * cs[j] - im * sn[j];
            k[2*j+1] = re * sn[j] + im * cs[j];
        }
    }

    // stage roped K and raw V into the per-wave LDS tile
    {
        float* krow = &kl[wv][h][p * 16];
        float* vrow = &vl[wv][h][p * 16];
        #pragma unroll
        for (int c = 0; c < 4; c++) {
            *(float4*)(krow + c*4) = make_float4(k[c*4], k[c*4+1], k[c*4+2], k[c*4+3]);
            *(float4*)(vrow + c*4) = make_float4(v[c*4], v[c*4+1], v[c*4+2], v[c*4+3]);
        }
    }

    // S[h][g] partial over this lane's 16 dims, then reduce across p
    float s[16];
    #pragma unroll
    for (int g = 0; g < 16; g++) {
        const float* kg = &kl[wv][g][p * 16];
        float4 a0 = *(const float4*)(kg);
        float4 a1 = *(const float4*)(kg + 4);
        float4 a2 = *(const float4*)(kg + 8);
        float4 a3 = *(const float4*)(kg + 12);
        s[g] = q[0]*a0.x + q[1]*a0.y + q[2]*a0.z + q[3]*a0.w
             + q[4]*a1.x + q[5]*a1.y + q[6]*a1.z + q[7]*a1.w
             + q[8]*a2.x + q[9]*a2.y + q[10]*a2.z + q[11]*a2.w
             + q[12]*a3.x + q[13]*a3.y + q[14]*a3.z + q[15]*a3.w;
    }
    #pragma unroll
    for (int g = 0; g < 16; g++) {
        s[g] += __shfl_xor(s[g], 16);
        s[g] += __shfl_xor(s[g], 32);
        s[g] *= 0.125f;
    }

    // lane-local softmax over g
    float m = s[0];
    #pragma unroll
    for (int g = 1; g < 16; g++) m = fmaxf(m, s[g]);
    float sum = 0.f;
    #pragma unroll
    for (int g = 0; g < 16; g++) { s[g] = __expf(s[g] - m); sum += s[g]; }
    const float inv = 1.0f / sum;

    // O[h][slice p] = sum_g P[g] * V[g][slice p]
    float o[16];
    #pragma unroll
    for (int i = 0; i < 16; i++) o[i] = 0.f;
    #pragma unroll
    for (int g = 0; g < 16; g++) {
        const float pg = s[g] * inv;
        const float* vg = &vl[wv][g][p * 16];
        float4 b0 = *(const float4*)(vg);
        float4 b1 = *(const float4*)(vg + 4);
        float4 b2 = *(const float4*)(vg + 8);
        float4 b3 = *(const float4*)(vg + 12);
        o[0]  += pg * b0.x; o[1]  += pg * b0.y; o[2]  += pg * b0.z; o[3]  += pg * b0.w;
        o[4]  += pg * b1.x; o[5]  += pg * b1.y; o[6]  += pg * b1.z; o[7]  += pg * b1.w;
        o[8]  += pg * b2.x; o[9]  += pg * b2.y; o[10] += pg * b2.z; o[11] += pg * b2.w;
        o[12] += pg * b3.x; o[13] += pg * b3.y; o[14] += pg * b3.z; o[15] += pg * b3.w;
    }

    uint4 r0, r1;
    r0.x = pack_bf16x2(o[0],  o[1]);  r0.y = pack_bf16x2(o[2],  o[3]);
    r0.z = pack_bf16x2(o[4],  o[5]);  r0.w = pack_bf16x2(o[6],  o[7]);
    r1.x = pack_bf16x2(o[8],  o[9]);  r1.y = pack_bf16x2(o[10], o[11]);
    r1.z = pack_bf16x2(o[12], o[13]); r1.w = pack_bf16x2(o[14], o[15]);
    unsigned short* ob = outb + (size_t)tok * DIM + h * 64 + p * 16;
    *(uint4*)(ob)     = r0;
    *(uint4*)(ob + 8) = r1;
}

// ---------------- launch ----------------
extern "C" void kernel_launch(void* const* d_in, const int* in_sizes, int n_in,
                              void* d_out, int out_size, void* d_ws, size_t ws_size,
                              hipStream_t stream) {
    const float* x      = (const float*)d_in[0];   // 16384 x 1024
    const float* fcos   = (const float*)d_in[1];   // 4096 x 32
    const float* fsin   = (const float*)d_in[2];
    const float* w_qkv  = (const float*)d_in[3];   // 1024 x 3072
    const float* g_q    = (const float*)d_in[4];
    const float* g_k    = (const float*)d_in[5];
    const float* w_proj = (const float*)d_in[6];   // 1024 x 1024
    const float* b_proj = (const float*)d_in[7];
    float* out = (float*)d_out;

    char* ws = (char*)d_ws;
    // workspace layout (bytes)
    unsigned short* xb      = (unsigned short*)(ws);                       // 33,554,432
    unsigned short* wqkvT   = (unsigned short*)(ws + 33554432);            //  6,291,456
    unsigned short* wprojT  = (unsigned short*)(ws + 39845888);            //  2,097,152
    unsigned short* qkv     = (unsigned short*)(ws + 41943040);            // 100,663,296
    unsigned short* attnout = (unsigned short*)(ws + 142606336);           // 33,554,432
    (void)ws_size; (void)in_sizes; (void)n_in; (void)out_size;

    // 1. casts / transposes
    {
        int n4 = (NTOK * DIM) / 4;   // 4,194,304
        cvt_f32_bf16<<<(n4 + 255) / 256, 256, 0, stream>>>(
            (const float4*)x, (ushort4*)xb, n4);
        transpose_cvt<<<dim3(K3 / 32, DIM / 32), dim3(32, 8), 0, stream>>>(
            w_qkv, wqkvT, DIM, K3);
        transpose_cvt<<<dim3(DIM / 32, DIM / 32), dim3(32, 8), 0, stream>>>(
            w_proj, wprojT, DIM, DIM);
    }
    // 2. qkv = x @ w_qkv   (bf16 out)  grid 64*12 = 768 (%8==0)
    gemm_bf16_256<0><<<dim3((NTOK / 256) * (K3 / 256)), 512, 0, stream>>>(
        xb, wqkvT, (void*)qkv, nullptr, NTOK, K3);
    // 3. per-token attention (wave per token, 4 tokens/block)
    attn_tok<<<NTOK / 4, 256, 0, stream>>>(qkv, fcos, fsin, g_q, g_k, attnout);
    // 4. out = attn @ w_proj + b   (fp32 out)  grid 64*4 = 256 (%8==0)
    gemm_bf16_256<1><<<dim3((NTOK / 256) * (DIM / 256)), 512, 0, stream>>>(
        attnout, wprojT, (void*)out, b_proj, NTOK, DIM);
}

// Round 3
// 330.194 us; speedup vs baseline: 1.0079x; 1.0079x over previous
//
#include <hip/hip_runtime.h>
#include <hip/hip_bf16.h>
#include <stddef.h>

// ---------------- problem constants ----------------
#define NTOK   16384          // b*n = 4*4096
#define SEQN   4096
#define DIM    1024
#define K3     3072           // 3*DIM
#define HEADS  16
#define HD     64             // head dim

typedef __attribute__((ext_vector_type(8)))  short  short8;
typedef __attribute__((ext_vector_type(4)))  float  float4v;

static __device__ __forceinline__ unsigned short f32_to_bf16_bits(float f) {
    unsigned u = __float_as_uint(f);
    unsigned r = u + 0x7fffu + ((u >> 16) & 1u);   // RNE
    return (unsigned short)(r >> 16);
}
static __device__ __forceinline__ unsigned pack_bf16x2(float lo, float hi) {
    return (unsigned)f32_to_bf16_bits(lo) | ((unsigned)f32_to_bf16_bits(hi) << 16);
}
static __device__ __forceinline__ void unpack_bf16x8(uint4 u, float* f) {
    f[0] = __uint_as_float(u.x << 16); f[1] = __uint_as_float(u.x & 0xffff0000u);
    f[2] = __uint_as_float(u.y << 16); f[3] = __uint_as_float(u.y & 0xffff0000u);
    f[4] = __uint_as_float(u.z << 16); f[5] = __uint_as_float(u.z & 0xffff0000u);
    f[6] = __uint_as_float(u.w << 16); f[7] = __uint_as_float(u.w & 0xffff0000u);
}

// async global->LDS DMA, 16B per lane, LDS dst = uniform base + lane*16
typedef const void __attribute__((address_space(1)))* gas_ptr;
typedef void __attribute__((address_space(3)))* las_ptr;
static __device__ __forceinline__ void gload_lds16(const unsigned short* g,
                                                   unsigned short* l) {
    __builtin_amdgcn_global_load_lds((gas_ptr)g, (las_ptr)l, 16, 0, 0);
}

// ---------------- prep: fp32 -> bf16 cast (vectorized) ----------------
__global__ void cvt_f32_bf16(const float4* __restrict__ in,
                             ushort4* __restrict__ out, int n4) {
    int i = blockIdx.x * blockDim.x + threadIdx.x;
    if (i < n4) {
        float4 v = in[i];
        ushort4 o;
        o.x = f32_to_bf16_bits(v.x);
        o.y = f32_to_bf16_bits(v.y);
        o.z = f32_to_bf16_bits(v.z);
        o.w = f32_to_bf16_bits(v.w);
        out[i] = o;
    }
}

// ---------------- prep: transpose K x N fp32 -> N x K bf16 ----------------
__global__ void transpose_cvt(const float* __restrict__ in,
                              unsigned short* __restrict__ out,
                              int K, int N) {
    __shared__ float t[32][33];
    int n0 = blockIdx.x * 32, k0 = blockIdx.y * 32;
    int tx = threadIdx.x, ty = threadIdx.y;     // block (32,8)
    #pragma unroll
    for (int r = ty; r < 32; r += 8)
        t[r][tx] = in[(size_t)(k0 + r) * N + n0 + tx];
    __syncthreads();
    #pragma unroll
    for (int r = ty; r < 32; r += 8)
        out[(size_t)(n0 + r) * K + k0 + tx] = f32_to_bf16_bits(t[tx][r]);
}

// ======== 256x256 bf16 GEMM, overlapped-segment schedule (R3) ========
// C[M,N] = A[M,K] * Bt[N,K]^T.  512 thr = 8 waves (2M x 4N), each wave a
// 128x64 strip of 8x4 16x16 fragments.  BK=64, double-buffered 128 KiB LDS.
// R3 restructure: each K-tile = 4 segments, each [MM_q || RD_{q+1} || STG]
// + ONE barrier — the quadrant q+1's ds_reads are issued in segment q so
// LDS drain overlaps MFMA issue (data consumed one segment later via
// compiler lgkmcnt).  Quadrant snake (0,0)(0,1)(1,1)(1,0) makes this work
// with ZERO extra fragment registers:
//   seg0: RD bF1       ; MM(0,0)[aF,b0F] ; STG Ae          ; BAR
//   seg1: MM(0,1)[aF,b1F]; RD aF(a=1) (WAR: after MM issue); STG Be ; BAR
//   seg2: MM(1,1)[aF,b1F];                                 STG Bo  ; BAR
//   seg3: MM(1,0)[aF,b0F]; VM(6); RD next-tile aF0,b0F     ; STG Ao ; BAR
// Restage invariant (unit staged >=1 barrier after its last read) holds:
// Ae/Be last read prev.seg3, Bo read seg0, Ao read seg1.  VM(6) before
// seg3's reads: the 6 newest outstanding loads = this tile's Ae,Be,Bo
// stages, so everything through next tile's Ao has landed.  Tail: VM(0)+BAR
// before tile-15 reads; tile 15 barrier-free.
// XOR swizzle chunk^=(row&7) on the GLOBAL side of the DMA (LDS dst linear,
// m104/m108), mirrored in fragment reads (0 bank conflicts, verified R1/R2).
template<int WITH_BIAS>
__global__ __launch_bounds__(512, 2) void gemm_bf16_256(
    const unsigned short* __restrict__ A,
    const unsigned short* __restrict__ Bt,
    void* __restrict__ Cout,
    const float* __restrict__ bias,
    int M, int N)
{
    constexpr int K = 1024;            // both GEMMs have K=1024
    __shared__ unsigned short As[2][256][64];   // 64 KiB
    __shared__ unsigned short Bs[2][256][64];   // 64 KiB

    const int tid  = threadIdx.x;
    const int wave = tid >> 6;
    const int lane = tid & 63;
    const int wm   = wave >> 2;        // 0..1
    const int wn   = wave & 3;         // 0..3
    const int l15  = lane & 15;
    const int l4   = lane >> 4;        // 0..3
    const int l7   = lane & 7;

    // T1: bijective XCD swizzle (grid % 8 == 0 at both call sites)
    const int nwg = (int)gridDim.x;
    const int bid = (int)blockIdx.x;
    const int swz = (bid & 7) * (nwg >> 3) + (bid >> 3);
    const int ntn = N >> 8;
    const int rowBase = (swz / ntn) << 8;
    const int colBase = (swz % ntn) << 8;
    (void)M;

    // staging lane geometry: 1 issue = 8 rows x 128 B
    const int drow = lane >> 3;        // 0..7
    const int lc   = l7 ^ drow;        // logical chunk fetched (pre-swizzle)
    const unsigned short* gA = A  + (size_t)(rowBase + drow) * K + lc * 8;
    const unsigned short* gB = Bt + (size_t)(colBase + drow) * K + lc * 8;

    float4v acc[8][4];
    #pragma unroll
    for (int m = 0; m < 8; m++)
        #pragma unroll
        for (int n = 0; n < 4; n++) acc[m][n] = (float4v)0.0f;

    short8 aF[4][2], b0F[2][2], b1F[2][2];

// ---- stage macros: one unit = 128 rows = 2 issues/wave (16 rows) ----
#define STG_A(f, oddH, T) do {                                               \
    const int ra_ = ((wave >> 2) * 128) + (oddH) * 64 + (wave & 3) * 16;     \
    gload_lds16(gA + (size_t)(ra_    ) * K + (size_t)(T) * 64, &As[f][ra_    ][0]); \
    gload_lds16(gA + (size_t)(ra_ + 8) * K + (size_t)(T) * 64, &As[f][ra_ + 8][0]); \
  } while (0)
#define STG_B(f, oddH, T) do {                                               \
    const int rb_ = ((wave >> 1) * 64) + (oddH) * 32 + (wave & 1) * 16;      \
    gload_lds16(gB + (size_t)(rb_    ) * K + (size_t)(T) * 64, &Bs[f][rb_    ][0]); \
    gload_lds16(gB + (size_t)(rb_ + 8) * K + (size_t)(T) * 64, &Bs[f][rb_ + 8][0]); \
  } while (0)

// ---- fragment reads (ds_read_b128, swizzled): chunk = kc*4+l4 ^ (row&7) ----
#define RD_A(f, a) do {                                                      \
    _Pragma("unroll")                                                        \
    for (int ra = 0; ra < 4; ra++) {                                         \
      const unsigned short* r_ = &As[f][wm * 128 + (a) * 64 + ra * 16 + l15][0]; \
      aF[ra][0] = *(const short8*)(r_ + (((    l4) ^ l7) * 8));              \
      aF[ra][1] = *(const short8*)(r_ + (((4 + l4) ^ l7) * 8));              \
    } } while (0)
#define RD_B(f, b, dst) do {                                                 \
    _Pragma("unroll")                                                        \
    for (int cb = 0; cb < 2; cb++) {                                         \
      const unsigned short* r_ = &Bs[f][wn * 64 + (b) * 32 + cb * 16 + l15][0]; \
      dst[cb][0] = *(const short8*)(r_ + (((    l4) ^ l7) * 8));             \
      dst[cb][1] = *(const short8*)(r_ + (((4 + l4) ^ l7) * 8));             \
    } } while (0)

// ---- one quadrant = 16 MFMA ----
#define MM(a, b, bF) do {                                                    \
    _Pragma("unroll")                                                        \
    for (int ra = 0; ra < 4; ra++)                                           \
      _Pragma("unroll")                                                      \
      for (int cb = 0; cb < 2; cb++) {                                       \
        acc[(a)*4+ra][(b)*2+cb] = __builtin_amdgcn_mfma_f32_16x16x32_bf16(   \
            aF[ra][0], bF[cb][0], acc[(a)*4+ra][(b)*2+cb], 0, 0, 0);         \
        acc[(a)*4+ra][(b)*2+cb] = __builtin_amdgcn_mfma_f32_16x16x32_bf16(   \
            aF[ra][1], bF[cb][1], acc[(a)*4+ra][(b)*2+cb], 0, 0, 0);         \
      } } while (0)

#define BAR()   __builtin_amdgcn_s_barrier()
#define SB()    __builtin_amdgcn_sched_barrier(0)
#define VM(n)   asm volatile("s_waitcnt vmcnt(" #n ")" ::: "memory")
#define P1()    __builtin_amdgcn_s_setprio(1)
#define P0()    __builtin_amdgcn_s_setprio(0)

    // ---- prologue: stage tiles 0,1 fully; pre-read tile0 q0 fragments ----
    STG_A(0,0,0); STG_B(0,0,0); STG_B(0,1,0); STG_A(0,1,0);
    STG_A(1,0,1); STG_B(1,0,1); STG_B(1,1,1); STG_A(1,1,1);
    VM(8);                        // tile0 (oldest 8 loads) landed
    BAR();
    RD_A(0,0); RD_B(0,0,b0F);
    SB(); BAR();

    // ---- main loop: 7 iterations x 2 K-tiles (tiles 0..13) ----
    #pragma unroll 1
    for (int i = 0; i < 7; i++) {
        const int T0 = 2 * i + 2, T1 = 2 * i + 3;
        // ---------- K-tile 2i (buf0) --------------------------------------
        RD_B(0,1,b1F);                 STG_A(0,0,T0);
        P1(); MM(0,0,b0F); P0(); SB(); BAR();
        P1(); MM(0,1,b1F); P0(); RD_A(0,1);  STG_B(0,0,T0); SB(); BAR();
        P1(); MM(1,1,b1F); P0();             STG_B(0,1,T0); SB(); BAR();
        P1(); MM(1,0,b0F); P0(); VM(6);
        RD_A(1,0); RD_B(1,0,b0F);            STG_A(0,1,T0); SB(); BAR();
        // ---------- K-tile 2i+1 (buf1) ------------------------------------
        RD_B(1,1,b1F);                 STG_A(1,0,T1);
        P1(); MM(0,0,b0F); P0(); SB(); BAR();
        P1(); MM(0,1,b1F); P0(); RD_A(1,1);  STG_B(1,0,T1); SB(); BAR();
        P1(); MM(1,1,b1F); P0();             STG_B(1,1,T1); SB(); BAR();
        P1(); MM(1,0,b0F); P0(); VM(6);
        RD_A(0,0); RD_B(0,0,b0F);            STG_A(1,1,T1); SB(); BAR();
    }

    // ---- tile 14 (buf0): no staging; VM(0)+BAR before tile-15 reads ----
    RD_B(0,1,b1F);
    P1(); MM(0,0,b0F); P0(); SB(); BAR();
    P1(); MM(0,1,b1F); P0(); RD_A(0,1); SB(); BAR();
    P1(); MM(1,1,b1F); P0(); SB(); BAR();
    P1(); MM(1,0,b0F); P0(); VM(0); SB(); BAR();
    // ---- tile 15 (buf1): pure compute, no barriers ----
    RD_A(1,0); RD_B(1,0,b0F);
    RD_B(1,1,b1F);
    P1(); MM(0,0,b0F); P0();
    P1(); MM(0,1,b1F); P0(); RD_A(1,1);
    P1(); MM(1,1,b1F); P0();
    P1(); MM(1,0,b0F); P0();

    // ---- epilogue: D col = lane&15, row = (lane>>4)*4 + reg ----
    #pragma unroll
    for (int m = 0; m < 8; m++) {
        const int row = rowBase + wm * 128 + m * 16 + l4 * 4;
        #pragma unroll
        for (int n = 0; n < 4; n++) {
            const int col = colBase + wn * 64 + n * 16 + l15;
            if (WITH_BIAS) {
                const float bv = bias[col];
                #pragma unroll
                for (int r = 0; r < 4; r++)
                    ((float*)Cout)[(size_t)(row + r) * N + col] = acc[m][n][r] + bv;
            } else {
                #pragma unroll
                for (int r = 0; r < 4; r++)
                    ((unsigned short*)Cout)[(size_t)(row + r) * N + col] =
                        f32_to_bf16_bits(acc[m][n][r]);
            }
        }
    }
#undef STG_A
#undef STG_B
#undef RD_A
#undef RD_B
#undef MM
#undef BAR
#undef SB
#undef VM
#undef P1
#undef P0
}

// ---------------- per-token attention: wave-per-token, barrier-free --------
__global__ __launch_bounds__(256) void attn_tok(
    const unsigned short* __restrict__ qkv,   // NTOK x 3072 bf16
    const float* __restrict__ fcos,           // 4096 x 32
    const float* __restrict__ fsin,
    const float* __restrict__ gq,             // 64
    const float* __restrict__ gk,
    unsigned short* __restrict__ outb)        // NTOK x 1024 bf16
{
    __shared__ float kl[4][16][68];   // [wave][g][dim] stride 68: 2-way alias
    __shared__ float vl[4][16][68];

    const int tid  = threadIdx.x;
    const int wv   = tid >> 6;
    const int lane = tid & 63;
    const int h    = lane & 15;
    const int p    = lane >> 4;
    const int tok  = blockIdx.x * 4 + wv;
    const int n    = tok & (SEQN - 1);

    const unsigned short* base = qkv + (size_t)tok * K3 + h * 64 + p * 16;
    uint4 qr0 = *(const uint4*)(base);
    uint4 qr1 = *(const uint4*)(base + 8);
    uint4 kr0 = *(const uint4*)(base + DIM);
    uint4 kr1 = *(const uint4*)(base + DIM + 8);
    uint4 vr0 = *(const uint4*)(base + 2 * DIM);
    uint4 vr1 = *(const uint4*)(base + 2 * DIM + 8);

    float q[16], k[16], v[16];
    unpack_bf16x8(qr0, q); unpack_bf16x8(qr1, q + 8);
    unpack_bf16x8(kr0, k); unpack_bf16x8(kr1, k + 8);
    unpack_bf16x8(vr0, v); unpack_bf16x8(vr1, v + 8);

    // RMSNorm over the 64-dim head (reduce across the 4 p-slices)
    float ssq = 0.f, ssk = 0.f;
    #pragma unroll
    for (int i = 0; i < 16; i++) { ssq += q[i] * q[i]; ssk += k[i] * k[i]; }
    ssq += __shfl_xor(ssq, 16); ssq += __shfl_xor(ssq, 32);
    ssk += __shfl_xor(ssk, 16); ssk += __shfl_xor(ssk, 32);
    const float sq = 1.0f / (sqrtf(ssq) * 0.125f + 1e-6f);
    const float sk = 1.0f / (sqrtf(ssk) * 0.125f + 1e-6f);

    #pragma unroll
    for (int c = 0; c < 4; c++) {
        float4 gg = *(const float4*)(gq + p * 16 + c * 4);
        float4 gh = *(const float4*)(gk + p * 16 + c * 4);
        q[c*4+0] *= sq * gg.x; q[c*4+1] *= sq * gg.y;
        q[c*4+2] *= sq * gg.z; q[c*4+3] *= sq * gg.w;
        k[c*4+0] *= sk * gh.x; k[c*4+1] *= sk * gh.y;
        k[c*4+2] *= sk * gh.z; k[c*4+3] *= sk * gh.w;
    }

    // RoPE: local pair j -> global pair index 8p+j
    {
        const float* cb = fcos + n * 32 + p * 8;
        const float* sb = fsin + n * 32 + p * 8;
        float4 c0 = *(const float4*)cb, c1 = *(const float4*)(cb + 4);
        float4 s0 = *(const float4*)sb, s1 = *(const float4*)(sb + 4);
        float cs[8] = {c0.x,c0.y,c0.z,c0.w,c1.x,c1.y,c1.z,c1.w};
        float sn[8] = {s0.x,s0.y,s0.z,s0.w,s1.x,s1.y,s1.z,s1.w};
        #pragma unroll
        for (int j = 0; j < 8; j++) {
            float re = q[2*j], im = q[2*j+1];
            q[2*j]   = re * cs[j] - im * sn[j];
            q[2*j+1] = re * sn[j] + im * cs[j];
            re = k[2*j]; im = k[2*j+1];
            k[2*j]   = re * cs[j] - im * sn[j];
            k[2*j+1] = re * sn[j] + im * cs[j];
        }
    }

    // stage roped K and raw V into the per-wave LDS tile
    {
        float* krow = &kl[wv][h][p * 16];
        float* vrow = &vl[wv][h][p * 16];
        #pragma unroll
        for (int c = 0; c < 4; c++) {
            *(float4*)(krow + c*4) = make_float4(k[c*4], k[c*4+1], k[c*4+2], k[c*4+3]);
            *(float4*)(vrow + c*4) = make_float4(v[c*4], v[c*4+1], v[c*4+2], v[c*4+3]);
        }
    }

    // S[h][g] partial over this lane's 16 dims, then reduce across p
    float s[16];
    #pragma unroll
    for (int g = 0; g < 16; g++) {
        const float* kg = &kl[wv][g][p * 16];
        float4 a0 = *(const float4*)(kg);
        float4 a1 = *(const float4*)(kg + 4);
        float4 a2 = *(const float4*)(kg + 8);
        float4 a3 = *(const float4*)(kg + 12);
        s[g] = q[0]*a0.x + q[1]*a0.y + q[2]*a0.z + q[3]*a0.w
             + q[4]*a1.x + q[5]*a1.y + q[6]*a1.z + q[7]*a1.w
             + q[8]*a2.x + q[9]*a2.y + q[10]*a2.z + q[11]*a2.w
             + q[12]*a3.x + q[13]*a3.y + q[14]*a3.z + q[15]*a3.w;
    }
    #pragma unroll
    for (int g = 0; g < 16; g++) {
        s[g] += __shfl_xor(s[g], 16);
        s[g] += __shfl_xor(s[g], 32);
        s[g] *= 0.125f;
    }

    // lane-local softmax over g
    float m = s[0];
    #pragma unroll
    for (int g = 1; g < 16; g++) m = fmaxf(m, s[g]);
    float sum = 0.f;
    #pragma unroll
    for (int g = 0; g < 16; g++) { s[g] = __expf(s[g] - m); sum += s[g]; }
    const float inv = 1.0f / sum;

    // O[h][slice p] = sum_g P[g] * V[g][slice p]
    float o[16];
    #pragma unroll
    for (int i = 0; i < 16; i++) o[i] = 0.f;
    #pragma unroll
    for (int g = 0; g < 16; g++) {
        const float pg = s[g] * inv;
        const float* vg = &vl[wv][g][p * 16];
        float4 b0 = *(const float4*)(vg);
        float4 b1 = *(const float4*)(vg + 4);
        float4 b2 = *(const float4*)(vg + 8);
        float4 b3 = *(const float4*)(vg + 12);
        o[0]  += pg * b0.x; o[1]  += pg * b0.y; o[2]  += pg * b0.z; o[3]  += pg * b0.w;
        o[4]  += pg * b1.x; o[5]  += pg * b1.y; o[6]  += pg * b1.z; o[7]  += pg * b1.w;
        o[8]  += pg * b2.x; o[9]  += pg * b2.y; o[10] += pg * b2.z; o[11] += pg * b2.w;
        o[12] += pg * b3.x; o[13] += pg * b3.y; o[14] += pg * b3.z; o[15] += pg * b3.w;
    }

    uint4 r0, r1;
    r0.x = pack_bf16x2(o[0],  o[1]);  r0.y = pack_bf16x2(o[2],  o[3]);
    r0.z = pack_bf16x2(o[4],  o[5]);  r0.w = pack_bf16x2(o[6],  o[7]);
    r1.x = pack_bf16x2(o[8],  o[9]);  r1.y = pack_bf16x2(o[10], o[11]);
    r1.z = pack_bf16x2(o[12], o[13]); r1.w = pack_bf16x2(o[14], o[15]);
    unsigned short* ob = outb + (size_t)tok * DIM + h * 64 + p * 16;
    *(uint4*)(ob)     = r0;
    *(uint4*)(ob + 8) = r1;
}

// ---------------- launch ----------------
extern "C" void kernel_launch(void* const* d_in, const int* in_sizes, int n_in,
                              void* d_out, int out_size, void* d_ws, size_t ws_size,
                              hipStream_t stream) {
    const float* x      = (const float*)d_in[0];   // 16384 x 1024
    const float* fcos   = (const float*)d_in[1];   // 4096 x 32
    const float* fsin   = (const float*)d_in[2];
    const float* w_qkv  = (const float*)d_in[3];   // 1024 x 3072
    const float* g_q    = (const float*)d_in[4];
    const float* g_k    = (const float*)d_in[5];
    const float* w_proj = (const float*)d_in[6];   // 1024 x 1024
    const float* b_proj = (const float*)d_in[7];
    float* out = (float*)d_out;

    char* ws = (char*)d_ws;
    // workspace layout (bytes)
    unsigned short* xb      = (unsigned short*)(ws);                       // 33,554,432
    unsigned short* wqkvT   = (unsigned short*)(ws + 33554432);            //  6,291,456
    unsigned short* wprojT  = (unsigned short*)(ws + 39845888);            //  2,097,152
    unsigned short* qkv     = (unsigned short*)(ws + 41943040);            // 100,663,296
    unsigned short* attnout = (unsigned short*)(ws + 142606336);           // 33,554,432
    (void)ws_size; (void)in_sizes; (void)n_in; (void)out_size;

    // 1. casts / transposes
    {
        int n4 = (NTOK * DIM) / 4;   // 4,194,304
        cvt_f32_bf16<<<(n4 + 255) / 256, 256, 0, stream>>>(
            (const float4*)x, (ushort4*)xb, n4);
        transpose_cvt<<<dim3(K3 / 32, DIM / 32), dim3(32, 8), 0, stream>>>(
            w_qkv, wqkvT, DIM, K3);
        transpose_cvt<<<dim3(DIM / 32, DIM / 32), dim3(32, 8), 0, stream>>>(
            w_proj, wprojT, DIM, DIM);
    }
    // 2. qkv = x @ w_qkv   (bf16 out)  grid 64*12 = 768 (%8==0)
    gemm_bf16_256<0><<<dim3((NTOK / 256) * (K3 / 256)), 512, 0, stream>>>(
        xb, wqkvT, (void*)qkv, nullptr, NTOK, K3);
    // 3. per-token attention (wave per token, 4 tokens/block)
    attn_tok<<<NTOK / 4, 256, 0, stream>>>(qkv, fcos, fsin, g_q, g_k, attnout);
    // 4. out = attn @ w_proj + b   (fp32 out)  grid 64*4 = 256 (%8==0)
    gemm_bf16_256<1><<<dim3((NTOK / 256) * (DIM / 256)), 512, 0, stream>>>(
        attnout, wprojT, (void*)out, b_proj, NTOK, DIM);
}

// Round 6
// 318.552 us; speedup vs baseline: 1.0447x; 1.0365x over previous
//
#include <hip/hip_runtime.h>
#include <hip/hip_bf16.h>
#include <stddef.h>

// ---------------- problem constants ----------------
#define NTOK   16384          // b*n = 4*4096
#define SEQN   4096
#define DIM    1024
#define K3     3072           // 3*DIM
#define HEADS  16
#define HD     64             // head dim

typedef __attribute__((ext_vector_type(8)))  short  short8;
typedef __attribute__((ext_vector_type(4)))  float  float4v;

static __device__ __forceinline__ unsigned short f32_to_bf16_bits(float f) {
    unsigned u = __float_as_uint(f);
    unsigned r = u + 0x7fffu + ((u >> 16) & 1u);   // RNE
    return (unsigned short)(r >> 16);
}
static __device__ __forceinline__ unsigned pack_bf16x2(float lo, float hi) {
    return (unsigned)f32_to_bf16_bits(lo) | ((unsigned)f32_to_bf16_bits(hi) << 16);
}
static __device__ __forceinline__ void unpack_bf16x8(uint4 u, float* f) {
    f[0] = __uint_as_float(u.x << 16); f[1] = __uint_as_float(u.x & 0xffff0000u);
    f[2] = __uint_as_float(u.y << 16); f[3] = __uint_as_float(u.y & 0xffff0000u);
    f[4] = __uint_as_float(u.z << 16); f[5] = __uint_as_float(u.z & 0xffff0000u);
    f[6] = __uint_as_float(u.w << 16); f[7] = __uint_as_float(u.w & 0xffff0000u);
}
static __device__ __forceinline__ short8 pack8(const float* f) {
    uint4 u;
    u.x = pack_bf16x2(f[0], f[1]);
    u.y = pack_bf16x2(f[2], f[3]);
    u.z = pack_bf16x2(f[4], f[5]);
    u.w = pack_bf16x2(f[6], f[7]);
    return __builtin_bit_cast(short8, u);
}

// async global->LDS DMA, 16B per lane, LDS dst = uniform base + lane*16
typedef const void __attribute__((address_space(1)))* gas_ptr;
typedef void __attribute__((address_space(3)))* las_ptr;
static __device__ __forceinline__ void gload_lds16(const unsigned short* g,
                                                   unsigned short* l) {
    __builtin_amdgcn_global_load_lds((gas_ptr)g, (las_ptr)l, 16, 0, 0);
}

// ---------------- prep: fp32 -> bf16 cast (vectorized) ----------------
__global__ void cvt_f32_bf16(const float4* __restrict__ in,
                             ushort4* __restrict__ out, int n4) {
    int i = blockIdx.x * blockDim.x + threadIdx.x;
    if (i < n4) {
        float4 v = in[i];
        ushort4 o;
        o.x = f32_to_bf16_bits(v.x);
        o.y = f32_to_bf16_bits(v.y);
        o.z = f32_to_bf16_bits(v.z);
        o.w = f32_to_bf16_bits(v.w);
        out[i] = o;
    }
}

// ---------------- prep: transpose K x N fp32 -> N x K bf16 ----------------
__global__ void transpose_cvt(const float* __restrict__ in,
                              unsigned short* __restrict__ out,
                              int K, int N) {
    __shared__ float t[32][33];
    int n0 = blockIdx.x * 32, k0 = blockIdx.y * 32;
    int tx = threadIdx.x, ty = threadIdx.y;     // block (32,8)
    #pragma unroll
    for (int r = ty; r < 32; r += 8)
        t[r][tx] = in[(size_t)(k0 + r) * N + n0 + tx];
    __syncthreads();
    #pragma unroll
    for (int r = ty; r < 32; r += 8)
        out[(size_t)(n0 + r) * K + k0 + tx] = f32_to_bf16_bits(t[tx][r]);
}

// ======== 256x256 bf16 GEMM, overlapped-segment schedule (R3, kept) ========
template<int WITH_BIAS>
__global__ __launch_bounds__(512, 2) void gemm_bf16_256(
    const unsigned short* __restrict__ A,
    const unsigned short* __restrict__ Bt,
    void* __restrict__ Cout,
    const float* __restrict__ bias,
    int M, int N)
{
    constexpr int K = 1024;            // both GEMMs have K=1024
    __shared__ unsigned short As[2][256][64];   // 64 KiB
    __shared__ unsigned short Bs[2][256][64];   // 64 KiB

    const int tid  = threadIdx.x;
    const int wave = tid >> 6;
    const int lane = tid & 63;
    const int wm   = wave >> 2;        // 0..1
    const int wn   = wave & 3;         // 0..3
    const int l15  = lane & 15;
    const int l4   = lane >> 4;        // 0..3
    const int l7   = lane & 7;

    // T1: bijective XCD swizzle (grid % 8 == 0 at both call sites)
    const int nwg = (int)gridDim.x;
    const int bid = (int)blockIdx.x;
    const int swz = (bid & 7) * (nwg >> 3) + (bid >> 3);
    const int ntn = N >> 8;
    const int rowBase = (swz / ntn) << 8;
    const int colBase = (swz % ntn) << 8;
    (void)M;

    // staging lane geometry: 1 issue = 8 rows x 128 B
    const int drow = lane >> 3;        // 0..7
    const int lc   = l7 ^ drow;        // logical chunk fetched (pre-swizzle)
    const unsigned short* gA = A  + (size_t)(rowBase + drow) * K + lc * 8;
    const unsigned short* gB = Bt + (size_t)(colBase + drow) * K + lc * 8;

    float4v acc[8][4];
    #pragma unroll
    for (int m = 0; m < 8; m++)
        #pragma unroll
        for (int n = 0; n < 4; n++) acc[m][n] = (float4v)0.0f;

    short8 aF[4][2], b0F[2][2], b1F[2][2];

#define STG_A(f, oddH, T) do {                                               \
    const int ra_ = ((wave >> 2) * 128) + (oddH) * 64 + (wave & 3) * 16;     \
    gload_lds16(gA + (size_t)(ra_    ) * K + (size_t)(T) * 64, &As[f][ra_    ][0]); \
    gload_lds16(gA + (size_t)(ra_ + 8) * K + (size_t)(T) * 64, &As[f][ra_ + 8][0]); \
  } while (0)
#define STG_B(f, oddH, T) do {                                               \
    const int rb_ = ((wave >> 1) * 64) + (oddH) * 32 + (wave & 1) * 16;      \
    gload_lds16(gB + (size_t)(rb_    ) * K + (size_t)(T) * 64, &Bs[f][rb_    ][0]); \
    gload_lds16(gB + (size_t)(rb_ + 8) * K + (size_t)(T) * 64, &Bs[f][rb_ + 8][0]); \
  } while (0)

#define RD_A(f, a) do {                                                      \
    _Pragma("unroll")                                                        \
    for (int ra = 0; ra < 4; ra++) {                                         \
      const unsigned short* r_ = &As[f][wm * 128 + (a) * 64 + ra * 16 + l15][0]; \
      aF[ra][0] = *(const short8*)(r_ + (((    l4) ^ l7) * 8));              \
      aF[ra][1] = *(const short8*)(r_ + (((4 + l4) ^ l7) * 8));              \
    } } while (0)
#define RD_B(f, b, dst) do {                                                 \
    _Pragma("unroll")                                                        \
    for (int cb = 0; cb < 2; cb++) {                                         \
      const unsigned short* r_ = &Bs[f][wn * 64 + (b) * 32 + cb * 16 + l15][0]; \
      dst[cb][0] = *(const short8*)(r_ + (((    l4) ^ l7) * 8));             \
      dst[cb][1] = *(const short8*)(r_ + (((4 + l4) ^ l7) * 8));             \
    } } while (0)

#define MM(a, b, bF) do {                                                    \
    _Pragma("unroll")                                                        \
    for (int ra = 0; ra < 4; ra++)                                           \
      _Pragma("unroll")                                                      \
      for (int cb = 0; cb < 2; cb++) {                                       \
        acc[(a)*4+ra][(b)*2+cb] = __builtin_amdgcn_mfma_f32_16x16x32_bf16(   \
            aF[ra][0], bF[cb][0], acc[(a)*4+ra][(b)*2+cb], 0, 0, 0);         \
        acc[(a)*4+ra][(b)*2+cb] = __builtin_amdgcn_mfma_f32_16x16x32_bf16(   \
            aF[ra][1], bF[cb][1], acc[(a)*4+ra][(b)*2+cb], 0, 0, 0);         \
      } } while (0)

#define BAR()   __builtin_amdgcn_s_barrier()
#define SB()    __builtin_amdgcn_sched_barrier(0)
#define VM(n)   asm volatile("s_waitcnt vmcnt(" #n ")" ::: "memory")
#define P1()    __builtin_amdgcn_s_setprio(1)
#define P0()    __builtin_amdgcn_s_setprio(0)

    // ---- prologue: stage tiles 0,1 fully; pre-read tile0 q0 fragments ----
    STG_A(0,0,0); STG_B(0,0,0); STG_B(0,1,0); STG_A(0,1,0);
    STG_A(1,0,1); STG_B(1,0,1); STG_B(1,1,1); STG_A(1,1,1);
    VM(8);                        // tile0 (oldest 8 loads) landed
    BAR();
    RD_A(0,0); RD_B(0,0,b0F);
    SB(); BAR();

    // ---- main loop: 7 iterations x 2 K-tiles (tiles 0..13) ----
    #pragma unroll 1
    for (int i = 0; i < 7; i++) {
        const int T0 = 2 * i + 2, T1 = 2 * i + 3;
        // ---------- K-tile 2i (buf0) --------------------------------------
        RD_B(0,1,b1F);                 STG_A(0,0,T0);
        P1(); MM(0,0,b0F); P0(); SB(); BAR();
        P1(); MM(0,1,b1F); P0(); RD_A(0,1);  STG_B(0,0,T0); SB(); BAR();
        P1(); MM(1,1,b1F); P0();             STG_B(0,1,T0); SB(); BAR();
        P1(); MM(1,0,b0F); P0(); VM(6);
        RD_A(1,0); RD_B(1,0,b0F);            STG_A(0,1,T0); SB(); BAR();
        // ---------- K-tile 2i+1 (buf1) ------------------------------------
        RD_B(1,1,b1F);                 STG_A(1,0,T1);
        P1(); MM(0,0,b0F); P0(); SB(); BAR();
        P1(); MM(0,1,b1F); P0(); RD_A(1,1);  STG_B(1,0,T1); SB(); BAR();
        P1(); MM(1,1,b1F); P0();             STG_B(1,1,T1); SB(); BAR();
        P1(); MM(1,0,b0F); P0(); VM(6);
        RD_A(0,0); RD_B(0,0,b0F);            STG_A(1,1,T1); SB(); BAR();
    }

    // ---- tile 14 (buf0): no staging; VM(0)+BAR before tile-15 reads ----
    RD_B(0,1,b1F);
    P1(); MM(0,0,b0F); P0(); SB(); BAR();
    P1(); MM(0,1,b1F); P0(); RD_A(0,1); SB(); BAR();
    P1(); MM(1,1,b1F); P0(); SB(); BAR();
    P1(); MM(1,0,b0F); P0(); VM(0); SB(); BAR();
    // ---- tile 15 (buf1): pure compute, no barriers ----
    RD_A(1,0); RD_B(1,0,b0F);
    RD_B(1,1,b1F);
    P1(); MM(0,0,b0F); P0();
    P1(); MM(0,1,b1F); P0(); RD_A(1,1);
    P1(); MM(1,1,b1F); P0();
    P1(); MM(1,0,b0F); P0();

    // ---- epilogue: D col = lane&15, row = (lane>>4)*4 + reg ----
    #pragma unroll
    for (int m = 0; m < 8; m++) {
        const int row = rowBase + wm * 128 + m * 16 + l4 * 4;
        #pragma unroll
        for (int n = 0; n < 4; n++) {
            const int col = colBase + wn * 64 + n * 16 + l15;
            if (WITH_BIAS) {
                const float bv = bias[col];
                #pragma unroll
                for (int r = 0; r < 4; r++)
                    ((float*)Cout)[(size_t)(row + r) * N + col] = acc[m][n][r] + bv;
            } else {
                #pragma unroll
                for (int r = 0; r < 4; r++)
                    ((unsigned short*)Cout)[(size_t)(row + r) * N + col] =
                        f32_to_bf16_bits(acc[m][n][r]);
            }
        }
    }
#undef STG_A
#undef STG_B
#undef RD_A
#undef RD_B
#undef MM
#undef BAR
#undef SB
#undef VM
#undef P1
#undef P0
}

// ========== per-token attention via MFMA: wave/token, no LDS (v3) ==========
// Only intrinsic: mfma_f32_16x16x32_bf16 (harness-proven via the GEMM).
// Convention system pinned by the passing GEMM:
//   A-frag: lane holds A[row=l&15][k=(l>>4)*8+j], j=0..7
//   B-frag: lane holds B[k=(l>>4)*8+j][col=l&15]
//   D:      lane holds D[row=(l>>4)*4+r][col=l&15]
// QK^T (swapped: D = K . Q^T so lane(h,p) holds S[q=h][g=p*4+r]) uses a
// bf16 hi+residual split (6 MFMAs) for ~f32-accurate scores.  PV uses the
// same K=32 intrinsic with the 16 real k-slots DUPLICATED across both
// K-halves (slot k = (p&1)*8+j) and P scaled by 0.5*inv (pow2, bf16-exact)
// so the doubled sum is exact.  v3: fully divergence-free (no act branch,
// all lanes identical work) and union-free (bit_cast only) — R5's failure
// suspects were divergent-shfl / union-punning codegen.
__global__ __launch_bounds__(256) void attn_tok_mfma(
    const unsigned short* __restrict__ qkv,   // NTOK x 3072 bf16
    const float* __restrict__ fcos,           // 4096 x 32
    const float* __restrict__ fsin,
    const float* __restrict__ gq,             // 64
    const float* __restrict__ gk,
    unsigned short* __restrict__ outb)        // NTOK x 1024 bf16
{
    const int tid  = threadIdx.x;
    const int wv   = tid >> 6;
    const int lane = tid & 63;
    const int h    = lane & 15;      // frag row/col index
    const int p    = lane >> 4;      // k-group
    const int tok  = blockIdx.x * 4 + wv;
    const int n    = tok & (SEQN - 1);

    // ---- load Q,K in frag layout: row h, dims p*8..+7 (lo) / 32+p*8 (hi) --
    const unsigned short* base = qkv + (size_t)tok * K3 + h * 64 + p * 8;
    uint4 qlo = *(const uint4*)(base);
    uint4 qhi = *(const uint4*)(base + 32);
    uint4 klo = *(const uint4*)(base + DIM);
    uint4 khi = *(const uint4*)(base + DIM + 32);

    float q[16], k[16];
    unpack_bf16x8(qlo, q); unpack_bf16x8(qhi, q + 8);
    unpack_bf16x8(klo, k); unpack_bf16x8(khi, k + 8);

    // ---- RMSNorm over head dim (reduce across p-groups: xor 16, 32) ----
    float ssq = 0.f, ssk = 0.f;
    #pragma unroll
    for (int i = 0; i < 16; i++) { ssq += q[i] * q[i]; ssk += k[i] * k[i]; }
    ssq += __shfl_xor(ssq, 16); ssq += __shfl_xor(ssq, 32);
    ssk += __shfl_xor(ssk, 16); ssk += __shfl_xor(ssk, 32);
    const float sq = 1.0f / (sqrtf(ssq) * 0.125f + 1e-6f);
    const float sk = 1.0f / (sqrtf(ssk) * 0.125f + 1e-6f);

    {   // g-weights: dims p*8..+7 and 32+p*8..+7
        float4 g0 = *(const float4*)(gq + p * 8);
        float4 g1 = *(const float4*)(gq + p * 8 + 4);
        float4 g2 = *(const float4*)(gq + 32 + p * 8);
        float4 g3 = *(const float4*)(gq + 32 + p * 8 + 4);
        float4 h0 = *(const float4*)(gk + p * 8);
        float4 h1 = *(const float4*)(gk + p * 8 + 4);
        float4 h2 = *(const float4*)(gk + 32 + p * 8);
        float4 h3 = *(const float4*)(gk + 32 + p * 8 + 4);
        float gg[16] = {g0.x,g0.y,g0.z,g0.w, g1.x,g1.y,g1.z,g1.w,
                        g2.x,g2.y,g2.z,g2.w, g3.x,g3.y,g3.z,g3.w};
        float hh[16] = {h0.x,h0.y,h0.z,h0.w, h1.x,h1.y,h1.z,h1.w,
                        h2.x,h2.y,h2.z,h2.w, h3.x,h3.y,h3.z,h3.w};
        #pragma unroll
        for (int i = 0; i < 16; i++) { q[i] *= sq * gg[i]; k[i] *= sk * hh[i]; }
    }

    // ---- RoPE: lo-run pair idx p*4+j, hi-run pair idx 16+p*4+j ----
    {
        float4 c0 = *(const float4*)(fcos + n * 32 + p * 4);
        float4 c1 = *(const float4*)(fcos + n * 32 + 16 + p * 4);
        float4 s0 = *(const float4*)(fsin + n * 32 + p * 4);
        float4 s1 = *(const float4*)(fsin + n * 32 + 16 + p * 4);
        float cs[8] = {c0.x,c0.y,c0.z,c0.w, c1.x,c1.y,c1.z,c1.w};
        float sn[8] = {s0.x,s0.y,s0.z,s0.w, s1.x,s1.y,s1.z,s1.w};
        #pragma unroll
        for (int j = 0; j < 8; j++) {
            const int lo = (j < 4) ? 2*j : 8 + 2*(j-4);
            float re = q[lo], im = q[lo+1];
            q[lo]   = re * cs[j] - im * sn[j];
            q[lo+1] = re * sn[j] + im * cs[j];
            re = k[lo]; im = k[lo+1];
            k[lo]   = re * cs[j] - im * sn[j];
            k[lo+1] = re * sn[j] + im * cs[j];
        }
    }

    // fold softmax scale d^-0.5 = 0.125 into q (exact: pow2 exponent shift)
    #pragma unroll
    for (int i = 0; i < 16; i++) q[i] *= 0.125f;

    // ---- bf16 hi + residual split for ~f32-accurate S ----
    float qr[16], kr[16];
    #pragma unroll
    for (int i = 0; i < 16; i++) {
        qr[i] = q[i] - __uint_as_float((unsigned)f32_to_bf16_bits(q[i]) << 16);
        kr[i] = k[i] - __uint_as_float((unsigned)f32_to_bf16_bits(k[i]) << 16);
    }
    short8 qH0 = pack8(q),  qH1 = pack8(q + 8);
    short8 qL0 = pack8(qr), qL1 = pack8(qr + 8);
    short8 kH0 = pack8(k),  kH1 = pack8(k + 8);
    short8 kL0 = pack8(kr), kL1 = pack8(kr + 8);

    // ---- S^T = K . Q^T : lane(h,p) holds S[q=h][g=p*4+r], r=0..3 ----
    float4v st = (float4v)0.0f;
    st = __builtin_amdgcn_mfma_f32_16x16x32_bf16(kH0, qH0, st, 0, 0, 0);
    st = __builtin_amdgcn_mfma_f32_16x16x32_bf16(kH1, qH1, st, 0, 0, 0);
    st = __builtin_amdgcn_mfma_f32_16x16x32_bf16(kH0, qL0, st, 0, 0, 0);
    st = __builtin_amdgcn_mfma_f32_16x16x32_bf16(kH1, qL1, st, 0, 0, 0);
    st = __builtin_amdgcn_mfma_f32_16x16x32_bf16(kL0, qH0, st, 0, 0, 0);
    st = __builtin_amdgcn_mfma_f32_16x16x32_bf16(kL1, qH1, st, 0, 0, 0);

    // ---- softmax over g (4 local + xor16 + xor32; q-row lives on h) ----
    float m = fmaxf(fmaxf(st[0], st[1]), fmaxf(st[2], st[3]));
    m = fmaxf(m, __shfl_xor(m, 16));
    m = fmaxf(m, __shfl_xor(m, 32));
    float e0 = __expf(st[0] - m), e1 = __expf(st[1] - m);
    float e2 = __expf(st[2] - m), e3 = __expf(st[3] - m);
    float sum = e0 + e1 + e2 + e3;
    sum += __shfl_xor(sum, 16); sum += __shfl_xor(sum, 32);
    const float hinv = 0.5f / sum;   // 0.5x compensates duplicated K-halves

    // ---- gather P into K=32 A-frag with DUPLICATED halves: every lane
    //      (h,p) holds P[q=h][g=(p&1)*8+j]*0.5, j=0..7.  Sources: g=8ph+j
    //      lives on lane (h, p'=2*ph (+1)) reg j&3.  All lanes shfl. ----
    const unsigned pe01 = pack_bf16x2(e0 * hinv, e1 * hinv);
    const unsigned pe23 = pack_bf16x2(e2 * hinv, e3 * hinv);
    const int ph   = p & 1;
    const int src0 = h + 32 * ph;          // p' = 2*ph
    const int src1 = src0 + 16;            // p' = 2*ph+1
    uint4 pu;
    pu.x = (unsigned)__shfl((int)pe01, src0);
    pu.y = (unsigned)__shfl((int)pe23, src0);
    pu.z = (unsigned)__shfl((int)pe01, src1);
    pu.w = (unsigned)__shfl((int)pe23, src1);
    const short8 paF = __builtin_bit_cast(short8, pu);

    // ---- V B-frags (duplicated likewise): lane(h,p) holds
    //      V[g=(p&1)*8+j][d=db*16+h], j=0..7.  All lanes load. ----
    const unsigned short* vb = qkv + (size_t)tok * K3 + 2 * DIM
                             + (size_t)(ph * 8) * 64 + h;
    short8 bvf[4];
    #pragma unroll
    for (int db = 0; db < 4; db++) {
        const unsigned short* vd = vb + db * 16;
        uint4 w;
        w.x = (unsigned)vd[0 * 64] | ((unsigned)vd[1 * 64] << 16);
        w.y = (unsigned)vd[2 * 64] | ((unsigned)vd[3 * 64] << 16);
        w.z = (unsigned)vd[4 * 64] | ((unsigned)vd[5 * 64] << 16);
        w.w = (unsigned)vd[6 * 64] | ((unsigned)vd[7 * 64] << 16);
        bvf[db] = __builtin_bit_cast(short8, w);
    }

    // ---- O = P . V : lane holds O[q=p*4+r][d=db*16+h] ----
    float4v o0 = __builtin_amdgcn_mfma_f32_16x16x32_bf16(paF, bvf[0], (float4v)0.0f, 0, 0, 0);
    float4v o1 = __builtin_amdgcn_mfma_f32_16x16x32_bf16(paF, bvf[1], (float4v)0.0f, 0, 0, 0);
    float4v o2 = __builtin_amdgcn_mfma_f32_16x16x32_bf16(paF, bvf[2], (float4v)0.0f, 0, 0, 0);
    float4v o3 = __builtin_amdgcn_mfma_f32_16x16x32_bf16(paF, bvf[3], (float4v)0.0f, 0, 0, 0);

    unsigned short* ob = outb + (size_t)tok * DIM + (size_t)(p * 4) * 64 + h;
    #pragma unroll
    for (int r = 0; r < 4; r++) {
        ob[(size_t)r * 64 +  0] = f32_to_bf16_bits(o0[r]);
        ob[(size_t)r * 64 + 16] = f32_to_bf16_bits(o1[r]);
        ob[(size_t)r * 64 + 32] = f32_to_bf16_bits(o2[r]);
        ob[(size_t)r * 64 + 48] = f32_to_bf16_bits(o3[r]);
    }
}

// ---------------- launch ----------------
extern "C" void kernel_launch(void* const* d_in, const int* in_sizes, int n_in,
                              void* d_out, int out_size, void* d_ws, size_t ws_size,
                              hipStream_t stream) {
    const float* x      = (const float*)d_in[0];   // 16384 x 1024
    const float* fcos   = (const float*)d_in[1];   // 4096 x 32
    const float* fsin   = (const float*)d_in[2];
    const float* w_qkv  = (const float*)d_in[3];   // 1024 x 3072
    const float* g_q    = (const float*)d_in[4];
    const float* g_k    = (const float*)d_in[5];
    const float* w_proj = (const float*)d_in[6];   // 1024 x 1024
    const float* b_proj = (const float*)d_in[7];
    float* out = (float*)d_out;

    char* ws = (char*)d_ws;
    // workspace layout (bytes)
    unsigned short* xb      = (unsigned short*)(ws);                       // 33,554,432
    unsigned short* wqkvT   = (unsigned short*)(ws + 33554432);            //  6,291,456
    unsigned short* wprojT  = (unsigned short*)(ws + 39845888);            //  2,097,152
    unsigned short* qkv     = (unsigned short*)(ws + 41943040);            // 100,663,296
    unsigned short* attnout = (unsigned short*)(ws + 142606336);           // 33,554,432
    (void)ws_size; (void)in_sizes; (void)n_in; (void)out_size;

    // 1. casts / transposes
    {
        int n4 = (NTOK * DIM) / 4;   // 4,194,304
        cvt_f32_bf16<<<(n4 + 255) / 256, 256, 0, stream>>>(
            (const float4*)x, (ushort4*)xb, n4);
        transpose_cvt<<<dim3(K3 / 32, DIM / 32), dim3(32, 8), 0, stream>>>(
            w_qkv, wqkvT, DIM, K3);
        transpose_cvt<<<dim3(DIM / 32, DIM / 32), dim3(32, 8), 0, stream>>>(
            w_proj, wprojT, DIM, DIM);
    }
    // 2. qkv = x @ w_qkv   (bf16 out)  grid 64*12 = 768 (%8==0)
    gemm_bf16_256<0><<<dim3((NTOK / 256) * (K3 / 256)), 512, 0, stream>>>(
        xb, wqkvT, (void*)qkv, nullptr, NTOK, K3);
    // 3. per-token attention via MFMA (wave per token, 4 tokens/block)
    attn_tok_mfma<<<NTOK / 4, 256, 0, stream>>>(qkv, fcos, fsin, g_q, g_k, attnout);
    // 4. out = attn @ w_proj + b   (fp32 out)  grid 64*4 = 256 (%8==0)
    gemm_bf16_256<1><<<dim3((NTOK / 256) * (DIM / 256)), 512, 0, stream>>>(
        attnout, wprojT, (void*)out, b_proj, NTOK, DIM);
}